// Round 2
// baseline (246.946 us; speedup 1.0000x reference)
//
#include <hip/hip_runtime.h>
#include <hip/hip_bf16.h>

typedef __attribute__((ext_vector_type(8))) short short8;
typedef __attribute__((ext_vector_type(4))) float floatx4;

__device__ __forceinline__ unsigned short f2b(float f) {
  unsigned int v;
  __builtin_memcpy(&v, &f, 4);
  unsigned int r = (v + 0x7FFFu + ((v >> 16) & 1u)) >> 16;
  return (unsigned short)r;
}

__device__ __forceinline__ void async_copy16(const void* g, void* l) {
  __builtin_amdgcn_global_load_lds(
      (const __attribute__((address_space(1))) unsigned int*)g,
      (__attribute__((address_space(3))) unsigned int*)l, 16, 0, 0);
}

// fp32 -> bf16 (rne), n must be a multiple of 4; one float4 per thread.
__global__ __launch_bounds__(256) void cvt_f32_bf16_kernel(
    const float* __restrict__ src, unsigned short* __restrict__ dst, int n4)
{
  int i = blockIdx.x * 256 + threadIdx.x;
  if (i < n4) {
    floatx4 v = *(const floatx4*)(src + (size_t)i * 4);
    alignas(8) unsigned short r[4];
#pragma unroll
    for (int j = 0; j < 4; ++j) r[j] = f2b(v[j]);
    *(unsigned long long*)(dst + (size_t)i * 4) = *(const unsigned long long*)r;
  }
}

// C = A @ W^T + bias. A:[M,1024] bf16 row-major, W:[1024,1024] bf16 row-major,
// bias fp32. 128x128 tile, BK=32, m97 structure. blockIdx.z selects the
// (W,bias,Dst) triple for fused QKV. F32OUT selects fp32 output (final proj).
template <bool F32OUT>
__global__ __launch_bounds__(256) void gemm_bias_kernel(
    const unsigned short* __restrict__ A,
    const unsigned short* __restrict__ W0, const unsigned short* __restrict__ W1,
    const unsigned short* __restrict__ W2,
    const float* __restrict__ bias0, const float* __restrict__ bias1,
    const float* __restrict__ bias2,
    unsigned short* __restrict__ D0, unsigned short* __restrict__ D1,
    unsigned short* __restrict__ D2, float* __restrict__ DF)
{
  const int z = blockIdx.z;
  const unsigned short* W  = (z == 0) ? W0 : (z == 1) ? W1 : W2;
  const float* bias        = (z == 0) ? bias0 : (z == 1) ? bias1 : bias2;
  unsigned short* Dst      = (z == 0) ? D0 : (z == 1) ? D1 : D2;

  __shared__ alignas(16) unsigned short sA[128 * 32];
  __shared__ alignas(16) unsigned short sB[128 * 32];

  const int tid  = threadIdx.x;
  const int lane = tid & 63;
  const int wave = tid >> 6;
  const int col  = lane & 15;
  const int quad = lane >> 4;
  const int wm   = (wave >> 1) * 64;
  const int wn   = (wave & 1) * 64;
  const int m0   = blockIdx.y * 128;
  const int n0   = blockIdx.x * 128;

  floatx4 acc[4][4];
#pragma unroll
  for (int i = 0; i < 4; ++i)
#pragma unroll
    for (int j = 0; j < 4; ++j) acc[i][j] = (floatx4){0.f, 0.f, 0.f, 0.f};

  for (int k0 = 0; k0 < 1024; k0 += 32) {
    __syncthreads();
#pragma unroll
    for (int i = 0; i < 2; ++i) {
      int c   = i * 256 + tid;
      int row = c >> 2;
      int ko  = (c & 3) * 8;
      async_copy16(A + (size_t)(m0 + row) * 1024 + k0 + ko, sA + c * 8);
      async_copy16(W + (size_t)(n0 + row) * 1024 + k0 + ko, sB + c * 8);
    }
    __syncthreads();
    short8 af[4], bf[4];
#pragma unroll
    for (int mi = 0; mi < 4; ++mi)
      af[mi] = *(const short8*)(sA + (wm + mi * 16 + col) * 32 + quad * 8);
#pragma unroll
    for (int ni = 0; ni < 4; ++ni)
      bf[ni] = *(const short8*)(sB + (wn + ni * 16 + col) * 32 + quad * 8);
#pragma unroll
    for (int mi = 0; mi < 4; ++mi)
#pragma unroll
      for (int ni = 0; ni < 4; ++ni)
        acc[mi][ni] = __builtin_amdgcn_mfma_f32_16x16x32_bf16(af[mi], bf[ni], acc[mi][ni], 0, 0, 0);
  }

#pragma unroll
  for (int ni = 0; ni < 4; ++ni) {
    int n = n0 + wn + ni * 16 + col;
    float bv = bias[n];
#pragma unroll
    for (int mi = 0; mi < 4; ++mi) {
      int mbase = m0 + wm + mi * 16 + quad * 4;
#pragma unroll
      for (int r = 0; r < 4; ++r) {
        float val = acc[mi][ni][r] + bv;
        if (F32OUT) DF[(size_t)(mbase + r) * 1024 + n] = val;
        else        Dst[(size_t)(mbase + r) * 1024 + n] = f2b(val);
      }
    }
  }
}

// V [4096,1024] (= [b,t,h*64+d]) -> VT [32][64][2048] (= [bh][d][t]), bf16.
__global__ __launch_bounds__(256) void transpose_v_kernel(
    const unsigned short* __restrict__ V, unsigned short* __restrict__ VT)
{
  __shared__ alignas(16) unsigned short tile[64][72];
  const int bh = blockIdx.x;
  const int b = bh >> 4, h = bh & 15;
  const int t0 = blockIdx.y * 64;
  const int tid = threadIdx.x;

#pragma unroll
  for (int i = 0; i < 2; ++i) {
    int c = i * 256 + tid;
    int tr = c >> 3;
    int doff = (c & 7) * 8;
    short8 v = *(const short8*)(V + (size_t)(b * 2048 + t0 + tr) * 1024 + h * 64 + doff);
    *(short8*)(&tile[tr][doff]) = v;
  }
  __syncthreads();
#pragma unroll
  for (int i = 0; i < 2; ++i) {
    int c = i * 256 + tid;
    int d = c >> 3;
    int toff = (c & 7) * 8;
    alignas(16) unsigned short tmp[8];
#pragma unroll
    for (int j = 0; j < 8; ++j) tmp[j] = tile[toff + j][d];
    *(short8*)(VT + ((size_t)bh * 64 + d) * 2048 + t0 + toff) = *(const short8*)tmp;
  }
}

// Flash-style attention, max-free softmax (scores bounded: |S/8| <~ 3).
// One block per (bh, 64-row q-tile). LDS tiles as two 32-col slabs of [64][32].
__global__ __launch_bounds__(256) void attention_kernel(
    const unsigned short* __restrict__ Q, const unsigned short* __restrict__ K,
    const unsigned short* __restrict__ VT, unsigned short* __restrict__ CTX)
{
  __shared__ alignas(16) unsigned short sQ[2 * 64 * 32];
  __shared__ alignas(16) unsigned short sK[2 * 64 * 32];
  __shared__ alignas(16) unsigned short sV[2 * 64 * 32];
  __shared__ alignas(16) unsigned short sP[4][2 * 16 * 32];

  const int bh = blockIdx.x;
  const int b = bh >> 4, h = bh & 15;
  const int q0 = blockIdx.y * 64;
  const int tid  = threadIdx.x;
  const int lane = tid & 63;
  const int wave = tid >> 6;
  const int col  = lane & 15;
  const int quad = lane >> 4;

#pragma unroll
  for (int i = 0; i < 2; ++i) {
    int r = tid >> 2;
    int ko = (tid & 3) * 8;
    async_copy16(Q + (size_t)(b * 2048 + q0 + r) * 1024 + h * 64 + i * 32 + ko,
                 sQ + (i * 256 + tid) * 8);
  }
  __syncthreads();
  short8 qf[2];
  qf[0] = *(const short8*)(sQ + (wave * 16 + col) * 32 + quad * 8);
  qf[1] = *(const short8*)(sQ + 2048 + (wave * 16 + col) * 32 + quad * 8);

  floatx4 Oacc[4];
#pragma unroll
  for (int f = 0; f < 4; ++f) Oacc[f] = (floatx4){0.f, 0.f, 0.f, 0.f};
  float lacc[4] = {0.f, 0.f, 0.f, 0.f};
  const float scale = 0.125f;  // 1/sqrt(64)

  for (int kt = 0; kt < 2048; kt += 64) {
    __syncthreads();
#pragma unroll
    for (int i = 0; i < 2; ++i) {
      int r = tid >> 2;
      int ko = (tid & 3) * 8;
      async_copy16(K + (size_t)(b * 2048 + kt + r) * 1024 + h * 64 + i * 32 + ko,
                   sK + (i * 256 + tid) * 8);
      async_copy16(VT + ((size_t)bh * 64 + r) * 2048 + kt + i * 32 + ko,
                   sV + (i * 256 + tid) * 8);
    }
    __syncthreads();

    floatx4 S[4];
#pragma unroll
    for (int f = 0; f < 4; ++f) {
      S[f] = (floatx4){0.f, 0.f, 0.f, 0.f};
      short8 kf0 = *(const short8*)(sK + (f * 16 + col) * 32 + quad * 8);
      S[f] = __builtin_amdgcn_mfma_f32_16x16x32_bf16(qf[0], kf0, S[f], 0, 0, 0);
      short8 kf1 = *(const short8*)(sK + 2048 + (f * 16 + col) * 32 + quad * 8);
      S[f] = __builtin_amdgcn_mfma_f32_16x16x32_bf16(qf[1], kf1, S[f], 0, 0, 0);
    }

    float rs[4] = {0.f, 0.f, 0.f, 0.f};
#pragma unroll
    for (int f = 0; f < 4; ++f) {
      int slab = (f >> 1) * 512;
      int tcol = (f & 1) * 16 + col;
#pragma unroll
      for (int r = 0; r < 4; ++r) {
        float p = __expf(S[f][r] * scale);
        rs[r] += p;
        sP[wave][slab + (quad * 4 + r) * 32 + tcol] = f2b(p);
      }
    }
#pragma unroll
    for (int s = 1; s < 16; s <<= 1) {
#pragma unroll
      for (int r = 0; r < 4; ++r) rs[r] += __shfl_xor(rs[r], s, 64);
    }
#pragma unroll
    for (int r = 0; r < 4; ++r) lacc[r] += rs[r];

    __syncthreads();  // P visible; S-phase reads of sK done before next staging

    short8 pf0 = *(const short8*)(sP[wave] + col * 32 + quad * 8);
    short8 pf1 = *(const short8*)(sP[wave] + 512 + col * 32 + quad * 8);
#pragma unroll
    for (int f = 0; f < 4; ++f) {
      short8 vf0 = *(const short8*)(sV + (f * 16 + col) * 32 + quad * 8);
      Oacc[f] = __builtin_amdgcn_mfma_f32_16x16x32_bf16(pf0, vf0, Oacc[f], 0, 0, 0);
      short8 vf1 = *(const short8*)(sV + 2048 + (f * 16 + col) * 32 + quad * 8);
      Oacc[f] = __builtin_amdgcn_mfma_f32_16x16x32_bf16(pf1, vf1, Oacc[f], 0, 0, 0);
    }
  }

#pragma unroll
  for (int f = 0; f < 4; ++f) {
#pragma unroll
    for (int r = 0; r < 4; ++r) {
      int q = q0 + wave * 16 + quad * 4 + r;
      int d = f * 16 + col;
      CTX[(size_t)(b * 2048 + q) * 1024 + h * 64 + d] = f2b(Oacc[f][r] / lacc[r]);
    }
  }
}

extern "C" void kernel_launch(void* const* d_in, const int* in_sizes, int n_in,
                              void* d_out, int out_size, void* d_ws, size_t ws_size,
                              hipStream_t stream) {
  const float* x   = (const float*)d_in[0];
  const float* W_q = (const float*)d_in[1];
  const float* b_q = (const float*)d_in[2];
  const float* W_k = (const float*)d_in[3];
  const float* b_k = (const float*)d_in[4];
  const float* W_v = (const float*)d_in[5];
  const float* b_v = (const float*)d_in[6];
  const float* W_o = (const float*)d_in[7];
  const float* b_o = (const float*)d_in[8];
  float* out = (float*)d_out;

  const size_t NX = (size_t)4096 * 1024;   // 4,194,304
  const size_t NW = (size_t)1024 * 1024;   // 1,048,576

  unsigned short* p   = (unsigned short*)d_ws;
  unsigned short* xb  = p;  p += NX;
  unsigned short* Wqb = p;  p += NW;
  unsigned short* Wkb = p;  p += NW;
  unsigned short* Wvb = p;  p += NW;
  unsigned short* Wob = p;  p += NW;
  unsigned short* Q   = p;  p += NX;
  unsigned short* Kb  = p;  p += NX;
  unsigned short* V   = p;  p += NX;
  unsigned short* VT  = p;  p += NX;
  unsigned short* CTX = V;  // V is dead after transpose; reuse its slot

  dim3 blk(256);
  cvt_f32_bf16_kernel<<<dim3(NX / 4 / 256), blk, 0, stream>>>(x,   xb,  NX / 4);
  cvt_f32_bf16_kernel<<<dim3(NW / 4 / 256), blk, 0, stream>>>(W_q, Wqb, NW / 4);
  cvt_f32_bf16_kernel<<<dim3(NW / 4 / 256), blk, 0, stream>>>(W_k, Wkb, NW / 4);
  cvt_f32_bf16_kernel<<<dim3(NW / 4 / 256), blk, 0, stream>>>(W_v, Wvb, NW / 4);
  cvt_f32_bf16_kernel<<<dim3(NW / 4 / 256), blk, 0, stream>>>(W_o, Wob, NW / 4);

  gemm_bias_kernel<false><<<dim3(8, 32, 3), blk, 0, stream>>>(
      xb, Wqb, Wkb, Wvb, b_q, b_k, b_v, Q, Kb, V, nullptr);
  transpose_v_kernel<<<dim3(32, 32), blk, 0, stream>>>(V, VT);
  attention_kernel<<<dim3(32, 32), blk, 0, stream>>>(Q, Kb, VT, CTX);
  gemm_bias_kernel<true><<<dim3(8, 32, 1), blk, 0, stream>>>(
      CTX, Wob, Wob, Wob, b_o, b_o, b_o, nullptr, nullptr, nullptr, out);
}

// Round 3
// 221.840 us; speedup vs baseline: 1.1132x; 1.1132x over previous
//
#include <hip/hip_runtime.h>
#include <hip/hip_bf16.h>

typedef __attribute__((ext_vector_type(8))) short short8;
typedef __attribute__((ext_vector_type(4))) short short4v;
typedef __attribute__((ext_vector_type(4))) float floatx4;

__device__ __forceinline__ unsigned short f2b(float f) {
  unsigned int v;
  __builtin_memcpy(&v, &f, 4);
  unsigned int r = (v + 0x7FFFu + ((v >> 16) & 1u)) >> 16;
  return (unsigned short)r;
}

__device__ __forceinline__ void async_copy16(const void* g, void* l) {
  __builtin_amdgcn_global_load_lds(
      (const __attribute__((address_space(1))) unsigned int*)g,
      (__attribute__((address_space(3))) unsigned int*)l, 16, 0, 0);
}

// One launch converts x (1M float4 groups) + 4 weight matrices (256K groups each).
__global__ __launch_bounds__(256) void cvt_all_kernel(
    const float* __restrict__ x,
    const float* __restrict__ w0, const float* __restrict__ w1,
    const float* __restrict__ w2, const float* __restrict__ w3,
    unsigned short* __restrict__ xb,
    unsigned short* __restrict__ d0, unsigned short* __restrict__ d1,
    unsigned short* __restrict__ d2, unsigned short* __restrict__ d3)
{
  int gid = blockIdx.x * 256 + threadIdx.x;
  const float* src;
  unsigned short* dst;
  size_t off;
  if (gid < (1 << 20)) {
    src = x; dst = xb; off = gid;
  } else {
    int g = gid - (1 << 20);
    int w = g >> 18;
    off = g & 0x3FFFF;
    src = (w == 0) ? w0 : (w == 1) ? w1 : (w == 2) ? w2 : w3;
    dst = (w == 0) ? d0 : (w == 1) ? d1 : (w == 2) ? d2 : d3;
  }
  floatx4 v = *(const floatx4*)(src + off * 4);
  alignas(8) unsigned short r[4];
#pragma unroll
  for (int j = 0; j < 4; ++j) r[j] = f2b(v[j]);
  *(unsigned long long*)(dst + off * 4) = *(const unsigned long long*)r;
}

// C = A @ W^T + bias. A:[M,1024] bf16 row-major, W:[1024,1024] bf16 row-major,
// bias fp32. 128x128 tile, BK=32, m97 structure. blockIdx.z selects the
// (W,bias,Dst) triple for fused QKV. F32OUT selects fp32 output (final proj).
template <bool F32OUT>
__global__ __launch_bounds__(256) void gemm_bias_kernel(
    const unsigned short* __restrict__ A,
    const unsigned short* __restrict__ W0, const unsigned short* __restrict__ W1,
    const unsigned short* __restrict__ W2,
    const float* __restrict__ bias0, const float* __restrict__ bias1,
    const float* __restrict__ bias2,
    unsigned short* __restrict__ D0, unsigned short* __restrict__ D1,
    unsigned short* __restrict__ D2, float* __restrict__ DF)
{
  const int z = blockIdx.z;
  const unsigned short* W  = (z == 0) ? W0 : (z == 1) ? W1 : W2;
  const float* bias        = (z == 0) ? bias0 : (z == 1) ? bias1 : bias2;
  unsigned short* Dst      = (z == 0) ? D0 : (z == 1) ? D1 : D2;

  __shared__ alignas(16) unsigned short sA[128 * 32];
  __shared__ alignas(16) unsigned short sB[128 * 32];

  const int tid  = threadIdx.x;
  const int lane = tid & 63;
  const int wave = tid >> 6;
  const int col  = lane & 15;
  const int quad = lane >> 4;
  const int wm   = (wave >> 1) * 64;
  const int wn   = (wave & 1) * 64;
  const int m0   = blockIdx.y * 128;
  const int n0   = blockIdx.x * 128;

  floatx4 acc[4][4];
#pragma unroll
  for (int i = 0; i < 4; ++i)
#pragma unroll
    for (int j = 0; j < 4; ++j) acc[i][j] = (floatx4){0.f, 0.f, 0.f, 0.f};

  for (int k0 = 0; k0 < 1024; k0 += 32) {
    __syncthreads();
#pragma unroll
    for (int i = 0; i < 2; ++i) {
      int c   = i * 256 + tid;
      int row = c >> 2;
      int ko  = (c & 3) * 8;
      async_copy16(A + (size_t)(m0 + row) * 1024 + k0 + ko, sA + c * 8);
      async_copy16(W + (size_t)(n0 + row) * 1024 + k0 + ko, sB + c * 8);
    }
    __syncthreads();
    short8 af[4], bf[4];
#pragma unroll
    for (int mi = 0; mi < 4; ++mi)
      af[mi] = *(const short8*)(sA + (wm + mi * 16 + col) * 32 + quad * 8);
#pragma unroll
    for (int ni = 0; ni < 4; ++ni)
      bf[ni] = *(const short8*)(sB + (wn + ni * 16 + col) * 32 + quad * 8);
#pragma unroll
    for (int mi = 0; mi < 4; ++mi)
#pragma unroll
      for (int ni = 0; ni < 4; ++ni)
        acc[mi][ni] = __builtin_amdgcn_mfma_f32_16x16x32_bf16(af[mi], bf[ni], acc[mi][ni], 0, 0, 0);
  }

#pragma unroll
  for (int ni = 0; ni < 4; ++ni) {
    int n = n0 + wn + ni * 16 + col;
    float bv = bias[n];
#pragma unroll
    for (int mi = 0; mi < 4; ++mi) {
      int mbase = m0 + wm + mi * 16 + quad * 4;
#pragma unroll
      for (int r = 0; r < 4; ++r) {
        float val = acc[mi][ni][r] + bv;
        if (F32OUT) DF[(size_t)(mbase + r) * 1024 + n] = val;
        else        Dst[(size_t)(mbase + r) * 1024 + n] = f2b(val);
      }
    }
  }
}

// V [4096,1024] (= [b,t,h*64+d]) -> VT [32][64][2048] (= [bh][d][t]), bf16.
__global__ __launch_bounds__(256) void transpose_v_kernel(
    const unsigned short* __restrict__ V, unsigned short* __restrict__ VT)
{
  __shared__ alignas(16) unsigned short tile[64][72];
  const int bh = blockIdx.x;
  const int b = bh >> 4, h = bh & 15;
  const int t0 = blockIdx.y * 64;
  const int tid = threadIdx.x;

#pragma unroll
  for (int i = 0; i < 2; ++i) {
    int c = i * 256 + tid;
    int tr = c >> 3;
    int doff = (c & 7) * 8;
    short8 v = *(const short8*)(V + (size_t)(b * 2048 + t0 + tr) * 1024 + h * 64 + doff);
    *(short8*)(&tile[tr][doff]) = v;
  }
  __syncthreads();
#pragma unroll
  for (int i = 0; i < 2; ++i) {
    int c = i * 256 + tid;
    int d = c >> 3;
    int toff = (c & 7) * 8;
    alignas(16) unsigned short tmp[8];
#pragma unroll
    for (int j = 0; j < 8; ++j) tmp[j] = tile[toff + j][d];
    *(short8*)(VT + ((size_t)bh * 64 + d) * 2048 + t0 + toff) = *(const short8*)tmp;
  }
}

// Flash-style attention, max-free softmax (scores bounded: |S/8| <~ 3).
// One block per (bh, 64-row q-tile). LDS tiles as two 32-col slabs of [64][32].
// sP rows are padded to 36 shorts: write bank = quad*8 + (f&1)*8 + col>>1
// -> 4 disjoint 8-bank windows per quad, 2 lanes/bank (same dword) = free.
// sP is wave-private: no barrier between P-write and P-read (lgkmcnt orders it).
__global__ __launch_bounds__(256) void attention_kernel(
    const unsigned short* __restrict__ Q, const unsigned short* __restrict__ K,
    const unsigned short* __restrict__ VT, unsigned short* __restrict__ CTX)
{
  __shared__ alignas(16) unsigned short sQ[2 * 64 * 32];
  __shared__ alignas(16) unsigned short sK[2 * 64 * 32];
  __shared__ alignas(16) unsigned short sV[2 * 64 * 32];
  __shared__ alignas(16) unsigned short sP[4][2 * 16 * 36];  // stride-36 rows

  const int bh = blockIdx.x;
  const int b = bh >> 4, h = bh & 15;
  const int q0 = blockIdx.y * 64;
  const int tid  = threadIdx.x;
  const int lane = tid & 63;
  const int wave = tid >> 6;
  const int col  = lane & 15;
  const int quad = lane >> 4;

#pragma unroll
  for (int i = 0; i < 2; ++i) {
    int r = tid >> 2;
    int ko = (tid & 3) * 8;
    async_copy16(Q + (size_t)(b * 2048 + q0 + r) * 1024 + h * 64 + i * 32 + ko,
                 sQ + (i * 256 + tid) * 8);
  }
  __syncthreads();
  short8 qf[2];
  qf[0] = *(const short8*)(sQ + (wave * 16 + col) * 32 + quad * 8);
  qf[1] = *(const short8*)(sQ + 2048 + (wave * 16 + col) * 32 + quad * 8);

  floatx4 Oacc[4];
#pragma unroll
  for (int f = 0; f < 4; ++f) Oacc[f] = (floatx4){0.f, 0.f, 0.f, 0.f};
  float lacc[4] = {0.f, 0.f, 0.f, 0.f};  // per-lane partial row sums
  const float scale = 0.125f;  // 1/sqrt(64)

  unsigned short* myP = &sP[wave][0];

  for (int kt = 0; kt < 2048; kt += 64) {
    __syncthreads();
#pragma unroll
    for (int i = 0; i < 2; ++i) {
      int r = tid >> 2;
      int ko = (tid & 3) * 8;
      async_copy16(K + (size_t)(b * 2048 + kt + r) * 1024 + h * 64 + i * 32 + ko,
                   sK + (i * 256 + tid) * 8);
      async_copy16(VT + ((size_t)bh * 64 + r) * 2048 + kt + i * 32 + ko,
                   sV + (i * 256 + tid) * 8);
    }
    __syncthreads();

    floatx4 S[4];
#pragma unroll
    for (int f = 0; f < 4; ++f) {
      S[f] = (floatx4){0.f, 0.f, 0.f, 0.f};
      short8 kf0 = *(const short8*)(sK + (f * 16 + col) * 32 + quad * 8);
      S[f] = __builtin_amdgcn_mfma_f32_16x16x32_bf16(qf[0], kf0, S[f], 0, 0, 0);
      short8 kf1 = *(const short8*)(sK + 2048 + (f * 16 + col) * 32 + quad * 8);
      S[f] = __builtin_amdgcn_mfma_f32_16x16x32_bf16(qf[1], kf1, S[f], 0, 0, 0);
    }

#pragma unroll
    for (int f = 0; f < 4; ++f) {
      int base = (f >> 1) * 576 + (f & 1) * 16 + col;
#pragma unroll
      for (int r = 0; r < 4; ++r) {
        float p = __expf(S[f][r] * scale);
        lacc[r] += p;  // cross-lane part deferred to epilogue
        myP[base + (quad * 4 + r) * 36] = f2b(p);
      }
    }

    // no __syncthreads here: sP is wave-private; lgkmcnt orders write->read.
    short8 pf0, pf1;
    {
      const unsigned short* p0 = myP + col * 36 + quad * 8;
      short4v lo = *(const short4v*)p0;
      short4v hi = *(const short4v*)(p0 + 4);
      pf0 = (short8){lo[0], lo[1], lo[2], lo[3], hi[0], hi[1], hi[2], hi[3]};
      const unsigned short* p1 = p0 + 576;
      short4v lo1 = *(const short4v*)p1;
      short4v hi1 = *(const short4v*)(p1 + 4);
      pf1 = (short8){lo1[0], lo1[1], lo1[2], lo1[3], hi1[0], hi1[1], hi1[2], hi1[3]};
    }
#pragma unroll
    for (int f = 0; f < 4; ++f) {
      short8 vf0 = *(const short8*)(sV + (f * 16 + col) * 32 + quad * 8);
      Oacc[f] = __builtin_amdgcn_mfma_f32_16x16x32_bf16(pf0, vf0, Oacc[f], 0, 0, 0);
      short8 vf1 = *(const short8*)(sV + 2048 + (f * 16 + col) * 32 + quad * 8);
      Oacc[f] = __builtin_amdgcn_mfma_f32_16x16x32_bf16(pf1, vf1, Oacc[f], 0, 0, 0);
    }
  }

  // one-time cross-lane reduction over the 16 col-lanes
#pragma unroll
  for (int s = 1; s < 16; s <<= 1) {
#pragma unroll
    for (int r = 0; r < 4; ++r) lacc[r] += __shfl_xor(lacc[r], s, 64);
  }

#pragma unroll
  for (int f = 0; f < 4; ++f) {
#pragma unroll
    for (int r = 0; r < 4; ++r) {
      int q = q0 + wave * 16 + quad * 4 + r;
      int d = f * 16 + col;
      CTX[(size_t)(b * 2048 + q) * 1024 + h * 64 + d] = f2b(Oacc[f][r] / lacc[r]);
    }
  }
}

extern "C" void kernel_launch(void* const* d_in, const int* in_sizes, int n_in,
                              void* d_out, int out_size, void* d_ws, size_t ws_size,
                              hipStream_t stream) {
  const float* x   = (const float*)d_in[0];
  const float* W_q = (const float*)d_in[1];
  const float* b_q = (const float*)d_in[2];
  const float* W_k = (const float*)d_in[3];
  const float* b_k = (const float*)d_in[4];
  const float* W_v = (const float*)d_in[5];
  const float* b_v = (const float*)d_in[6];
  const float* W_o = (const float*)d_in[7];
  const float* b_o = (const float*)d_in[8];
  float* out = (float*)d_out;

  const size_t NX = (size_t)4096 * 1024;
  const size_t NW = (size_t)1024 * 1024;

  unsigned short* p   = (unsigned short*)d_ws;
  unsigned short* xb  = p;  p += NX;
  unsigned short* Wqb = p;  p += NW;
  unsigned short* Wkb = p;  p += NW;
  unsigned short* Wvb = p;  p += NW;
  unsigned short* Wob = p;  p += NW;
  unsigned short* Q   = p;  p += NX;
  unsigned short* Kb  = p;  p += NX;
  unsigned short* V   = p;  p += NX;
  unsigned short* VT  = p;  p += NX;
  unsigned short* CTX = V;  // V is dead after transpose; reuse its slot

  dim3 blk(256);
  // 2M float4 groups total: 1M for x + 4 x 256K for weights
  cvt_all_kernel<<<dim3(8192), blk, 0, stream>>>(
      x, W_q, W_k, W_v, W_o, xb, Wqb, Wkb, Wvb, Wob);

  gemm_bias_kernel<false><<<dim3(8, 32, 3), blk, 0, stream>>>(
      xb, Wqb, Wkb, Wvb, b_q, b_k, b_v, Q, Kb, V, nullptr);
  transpose_v_kernel<<<dim3(32, 32), blk, 0, stream>>>(V, VT);
  attention_kernel<<<dim3(32, 32), blk, 0, stream>>>(Q, Kb, VT, CTX);
  gemm_bias_kernel<true><<<dim3(8, 32, 1), blk, 0, stream>>>(
      CTX, Wob, Wob, Wob, b_o, b_o, b_o, nullptr, nullptr, nullptr, out);
}

// Round 4
// 215.781 us; speedup vs baseline: 1.1444x; 1.0281x over previous
//
#include <hip/hip_runtime.h>
#include <hip/hip_bf16.h>

typedef __attribute__((ext_vector_type(8))) short short8;
typedef __attribute__((ext_vector_type(4))) float floatx4;

__device__ __forceinline__ unsigned short f2b(float f) {
  unsigned int v;
  __builtin_memcpy(&v, &f, 4);
  unsigned int r = (v + 0x7FFFu + ((v >> 16) & 1u)) >> 16;
  return (unsigned short)r;
}

// pack two fp32 -> bf16x2 (low = a, high = b)
__device__ __forceinline__ unsigned int f2b_pk(float a, float b) {
#if __has_builtin(__builtin_amdgcn_cvt_pk_bf16_f32)
  typedef __attribute__((ext_vector_type(2))) __bf16 bf16x2;
  bf16x2 r = __builtin_amdgcn_cvt_pk_bf16_f32(a, b);
  unsigned int u;
  __builtin_memcpy(&u, &r, 4);
  return u;
#else
  return ((unsigned int)f2b(b) << 16) | (unsigned int)f2b(a);
#endif
}

__device__ __forceinline__ float fast_exp2(float x) {
#if __has_builtin(__builtin_amdgcn_exp2f)
  return __builtin_amdgcn_exp2f(x);
#else
  return __builtin_exp2f(x);
#endif
}

__device__ __forceinline__ void async_copy16(const void* g, void* l) {
  __builtin_amdgcn_global_load_lds(
      (const __attribute__((address_space(1))) unsigned int*)g,
      (__attribute__((address_space(3))) unsigned int*)l, 16, 0, 0);
}

// 0.125 (1/sqrt(dk)) * log2(e): folded into Q so attention uses exp2 directly.
#define QSCALE 0.18033688011112042f

// One launch converts x (1M float4 groups) + 4 weight matrices (256K groups each).
__global__ __launch_bounds__(256) void cvt_all_kernel(
    const float* __restrict__ x,
    const float* __restrict__ w0, const float* __restrict__ w1,
    const float* __restrict__ w2, const float* __restrict__ w3,
    unsigned short* __restrict__ xb,
    unsigned short* __restrict__ d0, unsigned short* __restrict__ d1,
    unsigned short* __restrict__ d2, unsigned short* __restrict__ d3)
{
  int gid = blockIdx.x * 256 + threadIdx.x;
  const float* src;
  unsigned short* dst;
  size_t off;
  if (gid < (1 << 20)) {
    src = x; dst = xb; off = gid;
  } else {
    int g = gid - (1 << 20);
    int w = g >> 18;
    off = g & 0x3FFFF;
    src = (w == 0) ? w0 : (w == 1) ? w1 : (w == 2) ? w2 : w3;
    dst = (w == 0) ? d0 : (w == 1) ? d1 : (w == 2) ? d2 : d3;
  }
  floatx4 v = *(const floatx4*)(src + off * 4);
  unsigned int lo = f2b_pk(v[0], v[1]), hi = f2b_pk(v[2], v[3]);
  unsigned long long r = ((unsigned long long)hi << 32) | lo;
  *(unsigned long long*)(dst + off * 4) = r;
}

// QKV GEMM: C = A @ W^T + bias, 128x128 tile, BK=32. z=0: Q (pre-scaled by
// QSCALE), z=1: K, z=2: V written transposed as VT[bh][d][t].
__global__ __launch_bounds__(256) void gemm_qkv_kernel(
    const unsigned short* __restrict__ A,
    const unsigned short* __restrict__ W0, const unsigned short* __restrict__ W1,
    const unsigned short* __restrict__ W2,
    const float* __restrict__ bias0, const float* __restrict__ bias1,
    const float* __restrict__ bias2,
    unsigned short* __restrict__ Qo, unsigned short* __restrict__ Ko,
    unsigned short* __restrict__ VTo)
{
  const int z = blockIdx.z;
  const unsigned short* W  = (z == 0) ? W0 : (z == 1) ? W1 : W2;
  const float* bias        = (z == 0) ? bias0 : (z == 1) ? bias1 : bias2;

  __shared__ alignas(16) unsigned short sA[128 * 32];
  __shared__ alignas(16) unsigned short sB[128 * 32];

  const int tid  = threadIdx.x;
  const int lane = tid & 63;
  const int wave = tid >> 6;
  const int col  = lane & 15;
  const int quad = lane >> 4;
  const int wm   = (wave >> 1) * 64;
  const int wn   = (wave & 1) * 64;
  const int m0   = blockIdx.y * 128;
  const int n0   = blockIdx.x * 128;

  floatx4 acc[4][4];
#pragma unroll
  for (int i = 0; i < 4; ++i)
#pragma unroll
    for (int j = 0; j < 4; ++j) acc[i][j] = (floatx4){0.f, 0.f, 0.f, 0.f};

  for (int k0 = 0; k0 < 1024; k0 += 32) {
    __syncthreads();
#pragma unroll
    for (int i = 0; i < 2; ++i) {
      int c   = i * 256 + tid;
      int row = c >> 2;
      int ko  = (c & 3) * 8;
      async_copy16(A + (size_t)(m0 + row) * 1024 + k0 + ko, sA + c * 8);
      async_copy16(W + (size_t)(n0 + row) * 1024 + k0 + ko, sB + c * 8);
    }
    __syncthreads();
    short8 af[4], bf[4];
#pragma unroll
    for (int mi = 0; mi < 4; ++mi)
      af[mi] = *(const short8*)(sA + (wm + mi * 16 + col) * 32 + quad * 8);
#pragma unroll
    for (int ni = 0; ni < 4; ++ni)
      bf[ni] = *(const short8*)(sB + (wn + ni * 16 + col) * 32 + quad * 8);
#pragma unroll
    for (int mi = 0; mi < 4; ++mi)
#pragma unroll
      for (int ni = 0; ni < 4; ++ni)
        acc[mi][ni] = __builtin_amdgcn_mfma_f32_16x16x32_bf16(af[mi], bf[ni], acc[mi][ni], 0, 0, 0);
  }

#pragma unroll
  for (int ni = 0; ni < 4; ++ni) {
    int n = n0 + wn + ni * 16 + col;
    float bv = bias[n];
#pragma unroll
    for (int mi = 0; mi < 4; ++mi) {
      int mbase = m0 + wm + mi * 16 + quad * 4;
#pragma unroll
      for (int r = 0; r < 4; ++r) {
        int m = mbase + r;
        float val = acc[mi][ni][r] + bv;
        if (z == 0) {
          Qo[(size_t)m * 1024 + n] = f2b(val * QSCALE);
        } else if (z == 1) {
          Ko[(size_t)m * 1024 + n] = f2b(val);
        } else {
          int d = n & 63, h = n >> 6;
          int bb = m >> 11, t = m & 2047;
          VTo[(((size_t)bb * 16 + h) * 64 + d) * 2048 + t] = f2b(val);
        }
      }
    }
  }
}

// Out-proj GEMM: 128(M)x64(N) tile for occupancy at N=1024; fp32 output.
__global__ __launch_bounds__(256) void gemm_out_kernel(
    const unsigned short* __restrict__ A, const unsigned short* __restrict__ W,
    const float* __restrict__ bias, float* __restrict__ DF)
{
  __shared__ alignas(16) unsigned short sA[128 * 32];
  __shared__ alignas(16) unsigned short sB[64 * 32];

  const int tid  = threadIdx.x;
  const int lane = tid & 63;
  const int wave = tid >> 6;
  const int col  = lane & 15;
  const int quad = lane >> 4;
  const int wm   = (wave >> 1) * 64;
  const int wn   = (wave & 1) * 32;
  const int m0   = blockIdx.y * 128;
  const int n0   = blockIdx.x * 64;

  floatx4 acc[4][2];
#pragma unroll
  for (int i = 0; i < 4; ++i)
#pragma unroll
    for (int j = 0; j < 2; ++j) acc[i][j] = (floatx4){0.f, 0.f, 0.f, 0.f};

  for (int k0 = 0; k0 < 1024; k0 += 32) {
    __syncthreads();
#pragma unroll
    for (int i = 0; i < 2; ++i) {
      int c   = i * 256 + tid;
      int row = c >> 2;
      int ko  = (c & 3) * 8;
      async_copy16(A + (size_t)(m0 + row) * 1024 + k0 + ko, sA + c * 8);
    }
    {
      int row = tid >> 2;
      int ko  = (tid & 3) * 8;
      async_copy16(W + (size_t)(n0 + row) * 1024 + k0 + ko, sB + tid * 8);
    }
    __syncthreads();
    short8 af[4], bf[2];
#pragma unroll
    for (int mi = 0; mi < 4; ++mi)
      af[mi] = *(const short8*)(sA + (wm + mi * 16 + col) * 32 + quad * 8);
#pragma unroll
    for (int ni = 0; ni < 2; ++ni)
      bf[ni] = *(const short8*)(sB + (wn + ni * 16 + col) * 32 + quad * 8);
#pragma unroll
    for (int mi = 0; mi < 4; ++mi)
#pragma unroll
      for (int ni = 0; ni < 2; ++ni)
        acc[mi][ni] = __builtin_amdgcn_mfma_f32_16x16x32_bf16(af[mi], bf[ni], acc[mi][ni], 0, 0, 0);
  }

#pragma unroll
  for (int ni = 0; ni < 2; ++ni) {
    int n = n0 + wn + ni * 16 + col;
    float bv = bias[n];
#pragma unroll
    for (int mi = 0; mi < 4; ++mi) {
      int mbase = m0 + wm + mi * 16 + quad * 4;
#pragma unroll
      for (int r = 0; r < 4; ++r)
        DF[(size_t)(mbase + r) * 1024 + n] = acc[mi][ni][r] + bv;
    }
  }
}

// Flash attention, max-free softmax. Q is pre-scaled by QSCALE so p=exp2(s).
// QK computed transposed (A=K,B=Q) so each lane holds 4 consecutive k for a
// fixed q=col -> packed b64 P-writes, b128 P-reads, scalar per-lane row sum.
__global__ __launch_bounds__(256) void attention_kernel(
    const unsigned short* __restrict__ Q, const unsigned short* __restrict__ K,
    const unsigned short* __restrict__ VT, unsigned short* __restrict__ CTX)
{
  __shared__ alignas(16) unsigned short sQ[2 * 64 * 32];
  __shared__ alignas(16) unsigned short sK[2 * 64 * 32];
  __shared__ alignas(16) unsigned short sV[2 * 64 * 32];
  __shared__ alignas(16) unsigned short sP[4][16 * 72];  // [wave][q=16 rows x 72]

  const int bh = blockIdx.x;
  const int b = bh >> 4, h = bh & 15;
  const int q0 = blockIdx.y * 64;
  const int tid  = threadIdx.x;
  const int lane = tid & 63;
  const int wave = tid >> 6;
  const int col  = lane & 15;
  const int quad = lane >> 4;

#pragma unroll
  for (int i = 0; i < 2; ++i) {
    int r = tid >> 2;
    int ko = (tid & 3) * 8;
    async_copy16(Q + (size_t)(b * 2048 + q0 + r) * 1024 + h * 64 + i * 32 + ko,
                 sQ + (i * 256 + tid) * 8);
  }
  __syncthreads();
  short8 qf[2];
  qf[0] = *(const short8*)(sQ + (wave * 16 + col) * 32 + quad * 8);
  qf[1] = *(const short8*)(sQ + 2048 + (wave * 16 + col) * 32 + quad * 8);

  floatx4 Oacc[4];
#pragma unroll
  for (int f = 0; f < 4; ++f) Oacc[f] = (floatx4){0.f, 0.f, 0.f, 0.f};
  float lacc = 0.f;  // per-lane partial sum for q = col

  unsigned short* myP = &sP[wave][0];

  for (int kt = 0; kt < 2048; kt += 64) {
    __syncthreads();
#pragma unroll
    for (int i = 0; i < 2; ++i) {
      int r = tid >> 2;
      int ko = (tid & 3) * 8;
      async_copy16(K + (size_t)(b * 2048 + kt + r) * 1024 + h * 64 + i * 32 + ko,
                   sK + (i * 256 + tid) * 8);
      async_copy16(VT + ((size_t)bh * 64 + r) * 2048 + kt + i * 32 + ko,
                   sV + (i * 256 + tid) * 8);
    }
    __syncthreads();

    // S^T blocks: rows k = f*16+quad*4+r, col q
    floatx4 ST[4];
#pragma unroll
    for (int f = 0; f < 4; ++f) {
      ST[f] = (floatx4){0.f, 0.f, 0.f, 0.f};
      short8 kf0 = *(const short8*)(sK + (f * 16 + col) * 32 + quad * 8);
      ST[f] = __builtin_amdgcn_mfma_f32_16x16x32_bf16(kf0, qf[0], ST[f], 0, 0, 0);
      short8 kf1 = *(const short8*)(sK + 2048 + (f * 16 + col) * 32 + quad * 8);
      ST[f] = __builtin_amdgcn_mfma_f32_16x16x32_bf16(kf1, qf[1], ST[f], 0, 0, 0);
    }

#pragma unroll
    for (int f = 0; f < 4; ++f) {
      float p0 = fast_exp2(ST[f][0]);
      float p1 = fast_exp2(ST[f][1]);
      float p2 = fast_exp2(ST[f][2]);
      float p3 = fast_exp2(ST[f][3]);
      lacc += (p0 + p1) + (p2 + p3);
      unsigned long long w =
          ((unsigned long long)f2b_pk(p2, p3) << 32) | f2b_pk(p0, p1);
      *(unsigned long long*)(myP + col * 72 + f * 16 + quad * 4) = w;
    }

    // wave-private sP: lgkmcnt orders write->read, no barrier needed.
    short8 pf0 = *(const short8*)(myP + col * 72 + quad * 8);
    short8 pf1 = *(const short8*)(myP + col * 72 + 32 + quad * 8);
#pragma unroll
    for (int f = 0; f < 4; ++f) {
      short8 vf0 = *(const short8*)(sV + (f * 16 + col) * 32 + quad * 8);
      Oacc[f] = __builtin_amdgcn_mfma_f32_16x16x32_bf16(pf0, vf0, Oacc[f], 0, 0, 0);
      short8 vf1 = *(const short8*)(sV + 2048 + (f * 16 + col) * 32 + quad * 8);
      Oacc[f] = __builtin_amdgcn_mfma_f32_16x16x32_bf16(pf1, vf1, Oacc[f], 0, 0, 0);
    }
  }

  // lacc holds partial sum for q=col over this quad's k slices; sum quads.
  lacc += __shfl_xor(lacc, 16, 64);
  lacc += __shfl_xor(lacc, 32, 64);
  // row sums for this lane's output rows q = quad*4+r
  float inv[4];
#pragma unroll
  for (int r = 0; r < 4; ++r) inv[r] = 1.f / __shfl(lacc, quad * 4 + r, 16);

#pragma unroll
  for (int f = 0; f < 4; ++f) {
#pragma unroll
    for (int r = 0; r < 4; ++r) {
      int q = q0 + wave * 16 + quad * 4 + r;
      int d = f * 16 + col;
      CTX[(size_t)(b * 2048 + q) * 1024 + h * 64 + d] = f2b(Oacc[f][r] * inv[r]);
    }
  }
}

extern "C" void kernel_launch(void* const* d_in, const int* in_sizes, int n_in,
                              void* d_out, int out_size, void* d_ws, size_t ws_size,
                              hipStream_t stream) {
  const float* x   = (const float*)d_in[0];
  const float* W_q = (const float*)d_in[1];
  const float* b_q = (const float*)d_in[2];
  const float* W_k = (const float*)d_in[3];
  const float* b_k = (const float*)d_in[4];
  const float* W_v = (const float*)d_in[5];
  const float* b_v = (const float*)d_in[6];
  const float* W_o = (const float*)d_in[7];
  const float* b_o = (const float*)d_in[8];
  float* out = (float*)d_out;

  const size_t NX = (size_t)4096 * 1024;
  const size_t NW = (size_t)1024 * 1024;

  unsigned short* p   = (unsigned short*)d_ws;
  unsigned short* xb  = p;  p += NX;
  unsigned short* Wqb = p;  p += NW;
  unsigned short* Wkb = p;  p += NW;
  unsigned short* Wvb = p;  p += NW;
  unsigned short* Wob = p;  p += NW;
  unsigned short* Q   = p;  p += NX;
  unsigned short* Kb  = p;  p += NX;
  unsigned short* VT  = p;  p += NX;  // [32][64][2048]
  unsigned short* CTX = p;  p += NX;

  dim3 blk(256);
  cvt_all_kernel<<<dim3(8192), blk, 0, stream>>>(
      x, W_q, W_k, W_v, W_o, xb, Wqb, Wkb, Wvb, Wob);
  gemm_qkv_kernel<<<dim3(8, 32, 3), blk, 0, stream>>>(
      xb, Wqb, Wkb, Wvb, b_q, b_k, b_v, Q, Kb, VT);
  attention_kernel<<<dim3(32, 32), blk, 0, stream>>>(Q, Kb, VT, CTX);
  gemm_out_kernel<<<dim3(16, 32), blk, 0, stream>>>(CTX, Wob, b_o, out);
}